// Round 2
// baseline (786.730 us; speedup 1.0000x reference)
//
#include <hip/hip_runtime.h>
#include <cstdint>
#include <cstddef>

#define HH    128
#define VV    256
#define NB    8
#define NROW  2048        /* NB*VV  rows of h      */
#define NEROW 524288      /* NB*VV*VV rows of e    */
#define PROJ  (NROW*HH)   /* 262144 floats         */
#define EPSV  1e-5f

typedef __attribute__((ext_vector_type(8))) short short8v;   // 8 bf16 = 4 VGPR
typedef __attribute__((ext_vector_type(4))) short short4v;   // 4 bf16 = 2 VGPR
typedef __attribute__((ext_vector_type(4))) float f32x4;
typedef __attribute__((ext_vector_type(4))) _Float16 f16x4;

__device__ inline float4 f4add(float4 a, float4 b) {
    return make_float4(a.x+b.x, a.y+b.y, a.z+b.z, a.w+b.w);
}

// fp32 -> bf16 round-to-nearest-even (bit trick)
__device__ inline unsigned short f2bf(float x) {
    unsigned u = __float_as_uint(x);
    return (unsigned short)((u + 0x7fffu + ((u >> 16) & 1u)) >> 16);
}
__device__ inline float bf2f(unsigned short h) {
    return __uint_as_float(((unsigned)h) << 16);
}
__device__ inline void split4(float4 v, short4v &hi, short4v &lo) {
    float a[4] = {v.x, v.y, v.z, v.w};
    #pragma unroll
    for (int i = 0; i < 4; ++i) {
        unsigned short h = f2bf(a[i]);
        hi[i] = (short)h;
        lo[i] = (short)f2bf(a[i] - bf2f(h));
    }
}
__device__ inline void split8(float4 a, float4 b, short8v &hi, short8v &lo) {
    float v[8] = {a.x, a.y, a.z, a.w, b.x, b.y, b.z, b.w};
    #pragma unroll
    for (int i = 0; i < 8; ++i) {
        unsigned short h = f2bf(v[i]);
        hi[i] = (short)h;
        lo[i] = (short)f2bf(v[i] - bf2f(h));
    }
}

// ---------------------------------------------------------------------------
// K1: Uh/Vh/Ah/Bh = h @ W^T + b. grid (64,4).
// ---------------------------------------------------------------------------
__global__ __launch_bounds__(256) void k1_proj(
    const float* __restrict__ h,
    const float* __restrict__ Uw, const float* __restrict__ Ub,
    const float* __restrict__ Vw, const float* __restrict__ Vb,
    const float* __restrict__ Aw, const float* __restrict__ Ab,
    const float* __restrict__ Bw, const float* __restrict__ Bb,
    float* __restrict__ ws)
{
    __shared__ float hs[32*136];
    const int t  = threadIdx.x;
    const int R0 = blockIdx.x * 32;
    const int m  = blockIdx.y;
    {
        const float4* src = (const float4*)(h + (size_t)R0*HH);
        #pragma unroll
        for (int ii = 0; ii < 4; ++ii) {
            int idx4 = t + 256*ii;
            int r = idx4 >> 5, c = idx4 & 31;
            *(float4*)&hs[r*136 + c*4] = src[idx4];
        }
    }
    __syncthreads();
    const int o0 = (t & 15) * 8;
    const int jg = t >> 4;
    const float* __restrict__ W  = (m==0)?Uw:(m==1)?Vw:(m==2)?Aw:Bw;
    const float* __restrict__ Bv = (m==0)?Ub:(m==1)?Vb:(m==2)?Ab:Bb;

    float acc[2][8];
    #pragma unroll
    for (int jj = 0; jj < 2; ++jj)
        #pragma unroll
        for (int d = 0; d < 8; ++d) acc[jj][d] = 0.f;
    for (int k4 = 0; k4 < 32; ++k4) {
        float4 w[8];
        #pragma unroll
        for (int d = 0; d < 8; ++d)
            w[d] = *(const float4*)(W + (size_t)(o0+d)*HH + k4*4);
        #pragma unroll
        for (int jj = 0; jj < 2; ++jj) {
            float4 ev = *(const float4*)&hs[(jg*2+jj)*136 + k4*4];
            #pragma unroll
            for (int d = 0; d < 8; ++d)
                acc[jj][d] += ev.x*w[d].x + ev.y*w[d].y
                            + ev.z*w[d].z + ev.w*w[d].w;
        }
    }
    float4 b0 = *(const float4*)(Bv + o0);
    float4 b1 = *(const float4*)(Bv + o0 + 4);
    float* outp = ws + (size_t)m * PROJ;
    #pragma unroll
    for (int jj = 0; jj < 2; ++jj) {
        int r = R0 + jg*2 + jj;
        float4 v0 = f4add(make_float4(acc[jj][0],acc[jj][1],acc[jj][2],acc[jj][3]), b0);
        float4 v1 = f4add(make_float4(acc[jj][4],acc[jj][5],acc[jj][6],acc[jj][7]), b1);
        *(float4*)(outp + (size_t)r*HH + o0)     = v0;
        *(float4*)(outp + (size_t)r*HH + o0 + 4) = v1;
    }
}

// ---------------------------------------------------------------------------
// K2: per (b,i) block over all j.  Swapped-operand MFMA: D = Cw * E^T, so
// D rows = o (lane holds 4 consecutive o), D cols = j (lane&15).
// e staged pre-split into bf16 hi/lo LDS tiles (conversion once per element).
// 8 phases of 32 j-rows, double-buffered, reg prefetch of phase p+1.
// HALF: write e_new as fp16 (range +-4, err ~1e-3) to halve write traffic.
// ---------------------------------------------------------------------------
template<int HALF>
__global__ __launch_bounds__(256, 3) void k2_main(
    const float* __restrict__ e,
    const int*   __restrict__ graph,
    const float* __restrict__ Cw, const float* __restrict__ Cb,
    const float* __restrict__ ws,
    float* __restrict__ agg_out,
    float* __restrict__ esum, float* __restrict__ esumsq,
    float* __restrict__ e_new_f, _Float16* __restrict__ e_new_h)
{
    __shared__ short sh[2][2][32*136];        // [buf][hi/lo][32 rows x 136] = 34.8KB
    const int t   = threadIdx.x;
    const int l   = t & 63;
    const int wv  = t >> 6;                   // wave 0..3
    const int bi  = blockIdx.x;               // b*V + i
    const int b   = bi >> 8;
    const int ob  = wv * 32;                  // wave's o-base
    const int lr  = l & 15;
    const int lg  = l >> 4;                   // 0..3
    const int lg4 = lg * 4, lg8 = lg * 8;

    const float* __restrict__ Vh = ws + (size_t)PROJ;
    const float* __restrict__ Ah = ws + 2*(size_t)PROJ;
    const float* __restrict__ Bh = ws + 3*(size_t)PROJ;

    // per-lane bias: bc4[nt] = Bh[bi, o..o+3] + Cb[o..o+3],  o = ob+nt*16+lg4
    f32x4 bc4[2];
    #pragma unroll
    for (int nt = 0; nt < 2; ++nt) {
        const int oo = ob + nt*16 + lg4;
        f32x4 bh = *(const f32x4*)(Bh + (size_t)bi*HH + oo);
        f32x4 cb = *(const f32x4*)(Cb + oo);
        bc4[nt] = bh + cb;
    }

    // A-operand (W) fragments in registers: row o = ob+nt*16+lr, k = kk*32+lg8
    short8v Whi[2][4], Wlo[2][4];
    #pragma unroll
    for (int nt = 0; nt < 2; ++nt)
        #pragma unroll
        for (int kk = 0; kk < 4; ++kk) {
            const float* wp = Cw + (size_t)(ob + nt*16 + lr)*HH + kk*32 + lg8;
            split8(*(const float4*)wp, *(const float4*)(wp + 4),
                   Whi[nt][kk], Wlo[nt][kk]);
        }

    const float4* esrc = (const float4*)(e + (size_t)bi * VV * HH);

    // prologue: stage phase 0 (32 rows = 1024 float4, 4 per thread)
    float4 pf[4];
    #pragma unroll
    for (int q = 0; q < 4; ++q) pf[q] = esrc[t + 256*q];
    #pragma unroll
    for (int q = 0; q < 4; ++q) {
        int idx4 = t + 256*q, r = idx4 >> 5, c4 = idx4 & 31;
        short4v hv, lv; split4(pf[q], hv, lv);
        *(short4v*)&sh[0][0][r*136 + c4*4] = hv;
        *(short4v*)&sh[0][1][r*136 + c4*4] = lv;
    }
    __syncthreads();

    f32x4 se4[2], sq4[2], agg4[2];
    #pragma unroll
    for (int nt = 0; nt < 2; ++nt) {
        se4[nt] = (f32x4)0.f; sq4[nt] = (f32x4)0.f; agg4[nt] = (f32x4)0.f;
    }

    #pragma unroll 1
    for (int p = 0; p < 8; ++p) {
        // issue next-phase global loads early
        if (p < 7) {
            const float4* s2 = esrc + (size_t)(p + 1) * 1024;
            #pragma unroll
            for (int q = 0; q < 4; ++q) pf[q] = s2[t + 256*q];
        }

        const short* hiT = &sh[p & 1][0][0];
        const short* loT = &sh[p & 1][1][0];
        f32x4 acc[2][2];
        #pragma unroll
        for (int mt = 0; mt < 2; ++mt)
            #pragma unroll
            for (int nt = 0; nt < 2; ++nt) acc[mt][nt] = (f32x4)0.f;

        #pragma unroll
        for (int kk = 0; kk < 4; ++kk) {
            short8v Eh[2], El[2];
            #pragma unroll
            for (int mt = 0; mt < 2; ++mt) {
                const int off = (mt*16 + lr)*136 + kk*32 + lg8;
                Eh[mt] = *(const short8v*)&hiT[off];
                El[mt] = *(const short8v*)&loT[off];
            }
            #pragma unroll
            for (int mt = 0; mt < 2; ++mt)
                #pragma unroll
                for (int nt = 0; nt < 2; ++nt) {
                    acc[mt][nt] = __builtin_amdgcn_mfma_f32_16x16x32_bf16(
                                      Whi[nt][kk], Eh[mt], acc[mt][nt], 0, 0, 0);
                    acc[mt][nt] = __builtin_amdgcn_mfma_f32_16x16x32_bf16(
                                      Wlo[nt][kk], Eh[mt], acc[mt][nt], 0, 0, 0);
                    acc[mt][nt] = __builtin_amdgcn_mfma_f32_16x16x32_bf16(
                                      Whi[nt][kk], El[mt], acc[mt][nt], 0, 0, 0);
                }
        }

        // epilogue: lane holds C[o = ob+nt*16+lg4+r][j = p*32+mt*16+lr]
        #pragma unroll
        for (int mt = 0; mt < 2; ++mt) {
            const int j = p*32 + mt*16 + lr;
            const size_t rowA = (size_t)(b*VV + j) * HH;
            const size_t rowE = ((size_t)bi*VV + j) * HH;
            const float gm = graph[(size_t)bi*VV + j] ? 0.f : 1.f;
            #pragma unroll
            for (int nt = 0; nt < 2; ++nt) {
                const int oo = ob + nt*16 + lg4;
                f32x4 A4 = *(const f32x4*)(Ah + rowA + oo);
                f32x4 V4 = *(const f32x4*)(Vh + rowA + oo);
                f32x4 en = acc[mt][nt] + bc4[nt] + A4;
                if (HALF) {
                    f16x4 hv;
                    #pragma unroll
                    for (int c = 0; c < 4; ++c) hv[c] = (_Float16)en[c];
                    *(f16x4*)&e_new_h[rowE + oo] = hv;
                } else {
                    *(f32x4*)&e_new_f[rowE + oo] = en;
                }
                se4[nt] += en;
                sq4[nt] += en * en;
                f32x4 sg;
                #pragma unroll
                for (int c = 0; c < 4; ++c)
                    sg[c] = 1.f / (1.f + __expf(-en[c]));
                agg4[nt] += (gm * V4) * sg;
            }
        }

        // convert + write next phase into the other buffer
        if (p < 7) {
            short* dh = &sh[(p+1) & 1][0][0];
            short* dl = &sh[(p+1) & 1][1][0];
            #pragma unroll
            for (int q = 0; q < 4; ++q) {
                int idx4 = t + 256*q, r = idx4 >> 5, c4 = idx4 & 31;
                short4v hv, lv; split4(pf[q], hv, lv);
                *(short4v*)&dh[r*136 + c4*4] = hv;
                *(short4v*)&dl[r*136 + c4*4] = lv;
            }
            __syncthreads();
        }
    }

    // reduce over lr (lanes differing in bits 0..3 share the same o-quad)
    #pragma unroll
    for (int m = 1; m < 16; m <<= 1) {
        #pragma unroll
        for (int nt = 0; nt < 2; ++nt)
            #pragma unroll
            for (int c = 0; c < 4; ++c) {
                se4[nt][c]  += __shfl_xor(se4[nt][c],  m);
                sq4[nt][c]  += __shfl_xor(sq4[nt][c],  m);
                agg4[nt][c] += __shfl_xor(agg4[nt][c], m);
            }
    }
    if (lr == 0) {
        #pragma unroll
        for (int nt = 0; nt < 2; ++nt) {
            const int oo = ob + nt*16 + lg4;
            *(f32x4*)&agg_out[(size_t)bi*HH + oo] = agg4[nt];
            #pragma unroll
            for (int c = 0; c < 4; ++c) {
                atomicAdd(&esum[oo + c],   se4[nt][c]);
                atomicAdd(&esumsq[oo + c], sq4[nt][c]);
            }
        }
    }
}

// ---------------------------------------------------------------------------
// K3a: h_new = Uh + agg, plus per-channel sum/sumsq. grid 128, block 256.
// ---------------------------------------------------------------------------
__global__ __launch_bounds__(256) void k3a_hnew(
    const float* __restrict__ Uh, const float* __restrict__ agg,
    float* __restrict__ hnew, float* __restrict__ hsum, float* __restrict__ hsumsq)
{
    __shared__ float red[512];
    const int t = threadIdx.x;
    const int o = t & 127;
    const int g = t >> 7;
    const int R0 = blockIdx.x * 16;
    float s = 0.f, s2 = 0.f;
    #pragma unroll
    for (int rr = 0; rr < 8; ++rr) {
        size_t idx = (size_t)(R0 + g*8 + rr)*HH + o;
        float v = Uh[idx] + agg[idx];
        hnew[idx] = v;
        s += v; s2 += v*v;
    }
    red[t] = s; red[256 + t] = s2;
    __syncthreads();
    if (t < 128) {
        atomicAdd(&hsum[o],   red[t]     + red[t + 128]);
        atomicAdd(&hsumsq[o], red[256+t] + red[256 + t + 128]);
    }
}

// ---------------------------------------------------------------------------
// K3b: fold batchnorm into per-channel affine (a,c) for h and e. 1x128.
// ---------------------------------------------------------------------------
__global__ void k3b_coef(const float* __restrict__ st, float* __restrict__ coef,
    const float* __restrict__ gh, const float* __restrict__ bh,
    const float* __restrict__ ge, const float* __restrict__ be)
{
    int o = threadIdx.x;
    float es = st[o], eq = st[128+o], hs = st[256+o], hq = st[384+o];
    float me = es * (1.f/(float)NEROW);
    float ve = eq * (1.f/(float)NEROW) - me*me;
    float ae = ge[o] * rsqrtf(ve + EPSV);
    float ce = be[o] - me*ae;
    float mh = hs * (1.f/(float)NROW);
    float vh = hq * (1.f/(float)NROW) - mh*mh;
    float ah = gh[o] * rsqrtf(vh + EPSV);
    float ch = bh[o] - mh*ah;
    coef[o] = ah; coef[128+o] = ch; coef[256+o] = ae; coef[384+o] = ce;
}

// ---------------------------------------------------------------------------
// K3c: h_out = h_in + relu(a*h_new + c). grid 256, block 256.
// ---------------------------------------------------------------------------
__global__ __launch_bounds__(256) void k3c_hout(
    const float* __restrict__ h_in, const float* __restrict__ hnew,
    const float* __restrict__ coef, float* __restrict__ out_h)
{
    int idx = blockIdx.x*256 + threadIdx.x;
    int o4 = (idx & 31) * 4;
    float4 a = *(const float4*)(coef + o4);
    float4 c = *(const float4*)(coef + 128 + o4);
    float4 v = ((const float4*)hnew)[idx];
    float4 x = ((const float4*)h_in)[idx];
    float4 r;
    r.x = x.x + fmaxf(fmaf(a.x, v.x, c.x), 0.f);
    r.y = x.y + fmaxf(fmaf(a.y, v.y, c.y), 0.f);
    r.z = x.z + fmaxf(fmaf(a.z, v.z, c.z), 0.f);
    r.w = x.w + fmaxf(fmaf(a.w, v.w, c.w), 0.f);
    ((float4*)out_h)[idx] = r;
}

// ---------------------------------------------------------------------------
// K4: e_out = e_in + relu(a_e*e_new + c_e). HALF: e_new read as fp16.
// ---------------------------------------------------------------------------
template<int HALF>
__global__ __launch_bounds__(256) void k4_eout(
    const float* __restrict__ e_in, const float* __restrict__ coef,
    const void* __restrict__ enew, float* __restrict__ e_out)
{
    const size_t total4 = (size_t)NEROW * HH / 4;     // 16777216
    size_t idx = (size_t)blockIdx.x * 256 + threadIdx.x;
    const size_t stride = (size_t)gridDim.x * 256;    // % 32 == 0
    const int o4 = ((int)(idx & 31)) * 4;
    const float4 a = *(const float4*)(coef + 256 + o4);
    const float4 c = *(const float4*)(coef + 384 + o4);
    const float4* ein4 = (const float4*)e_in;
    for (; idx < total4; idx += stride) {
        float4 v;
        if (HALF) {
            f16x4 hv = ((const f16x4*)enew)[idx];
            v = make_float4((float)hv[0], (float)hv[1], (float)hv[2], (float)hv[3]);
        } else {
            v = ((const float4*)enew)[idx];
        }
        float4 x = ein4[idx];
        float4 r;
        r.x = x.x + fmaxf(fmaf(a.x, v.x, c.x), 0.f);
        r.y = x.y + fmaxf(fmaf(a.y, v.y, c.y), 0.f);
        r.z = x.z + fmaxf(fmaf(a.z, v.z, c.z), 0.f);
        r.w = x.w + fmaxf(fmaf(a.w, v.w, c.w), 0.f);
        ((float4*)e_out)[idx] = r;
    }
}

// ---------------------------------------------------------------------------
extern "C" void kernel_launch(void* const* d_in, const int* in_sizes, int n_in,
                              void* d_out, int out_size, void* d_ws, size_t ws_size,
                              hipStream_t stream)
{
    (void)in_sizes; (void)n_in; (void)out_size;
    const float* h     = (const float*)d_in[0];
    const float* e     = (const float*)d_in[1];
    const int*   graph = (const int*)  d_in[2];
    const float* Uw = (const float*)d_in[3];
    const float* Ub = (const float*)d_in[4];
    const float* Vw = (const float*)d_in[5];
    const float* Vb = (const float*)d_in[6];
    const float* Aw = (const float*)d_in[7];
    const float* Ab = (const float*)d_in[8];
    const float* Bw = (const float*)d_in[9];
    const float* Bb = (const float*)d_in[10];
    const float* Cw = (const float*)d_in[11];
    const float* Cb = (const float*)d_in[12];
    const float* gamma_h = (const float*)d_in[13];
    const float* beta_h  = (const float*)d_in[14];
    const float* gamma_e = (const float*)d_in[15];
    const float* beta_e  = (const float*)d_in[16];

    float* out_h = (float*)d_out;
    float* out_e = out_h + (size_t)NROW * HH;     // e_new scratch (fp32 path), then e_out

    float* ws    = (float*)d_ws;
    float* Uh    = ws;                            // [0,PROJ) U; then V,A,B
    float* aggp  = ws + 4*(size_t)PROJ;
    float* hnew  = ws + 5*(size_t)PROJ;
    float* stats = ws + 6*(size_t)PROJ;           // 512 sums + 512 coef
    float* coef  = stats + 512;

    // optional fp16 e_new buffer in workspace (128 MB), guarded by ws_size
    size_t base = ((size_t)(6*PROJ + 1024) * 4 + 255) & ~(size_t)255;
    size_t need = base + (size_t)NEROW * HH * 2;
    bool use_half = (ws_size >= need);
    _Float16* enh = (_Float16*)((char*)d_ws + base);

    hipMemsetAsync(stats, 0, 512*sizeof(float), stream);
    k1_proj<<<dim3(64, 4), 256, 0, stream>>>(h, Uw,Ub, Vw,Vb, Aw,Ab, Bw,Bb, ws);
    if (use_half) {
        k2_main<1><<<2048, 256, 0, stream>>>(e, graph, Cw, Cb, ws, aggp,
                                             stats, stats+128, out_e, enh);
    } else {
        k2_main<0><<<2048, 256, 0, stream>>>(e, graph, Cw, Cb, ws, aggp,
                                             stats, stats+128, out_e, enh);
    }
    k3a_hnew<<<128, 256, 0, stream>>>(Uh, aggp, hnew, stats+256, stats+384);
    k3b_coef<<<1, 128, 0, stream>>>(stats, coef, gamma_h, beta_h, gamma_e, beta_e);
    k3c_hout<<<256, 256, 0, stream>>>(h, hnew, coef, out_h);
    if (use_half) {
        k4_eout<1><<<8192, 256, 0, stream>>>(e, coef, enh, out_e);
    } else {
        k4_eout<0><<<8192, 256, 0, stream>>>(e, coef, out_e, out_e);
    }
}